// Round 7
// baseline (404.355 us; speedup 1.0000x reference)
//
#include <hip/hip_runtime.h>
#include <hip/hip_bf16.h>

#define IN_FEAT 256
#define OUT_FEAT 32

// ---- single-level partition geometry ----
#define RBC 256          // rows per bucket
#define NC_MAX 512       // max buckets (n_nodes <= 131072)
#define CAPC 4864        // capacity per bucket: lambda=4092 (+12 sigma)
#define L1_CHUNK 4096    // edges per part1 block (8 per thread, 512 threads)
#define SCH 2048         // consumer LDS staging chunk (entries)
#define OCAP 65536       // overflow list capacity
#define CNT_STRIDE 16    // u32 stride between counters (64B apart)

typedef __attribute__((ext_vector_type(8))) short short8;
typedef __attribute__((ext_vector_type(4))) float f32x4;

__device__ __forceinline__ unsigned cvt_pk_bf16(float lo, float hi) {
    unsigned r;
    asm volatile("v_cvt_pk_bf16_f32 %0, %1, %2" : "=v"(r) : "v"(lo), "v"(hi));
    return r;
}
__device__ __forceinline__ void nt_store_f32(float* p, float v) {
    __builtin_nontemporal_store(v, p);
}
__device__ __forceinline__ void nt_store_u64(uint2* p, uint2 v) {
    __builtin_nontemporal_store(*reinterpret_cast<unsigned long long*>(&v),
                                reinterpret_cast<unsigned long long*>(p));
}

// ---------------------------------------------------------------------------
// Kernel 1: x = feat @ W via bf16 MFMA (measured 27 us, unchanged).
// ---------------------------------------------------------------------------
__global__ __launch_bounds__(256) void gemm_mfma_kernel(
    const float* __restrict__ feat,
    const float* __restrict__ W,
    float* __restrict__ x,
    int n)
{
    __shared__ short sWT[OUT_FEAT][IN_FEAT + 8];

    const int tid = threadIdx.x;
    for (int i = tid; i < IN_FEAT * OUT_FEAT; i += 256) {
        const int k = i >> 5, c = i & 31;
        __hip_bfloat16 h = __float2bfloat16(W[i]);
        sWT[c][k] = *reinterpret_cast<short*>(&h);
    }
    __syncthreads();

    const int wid  = tid >> 6;
    const int lane = tid & 63;
    const int tile = blockIdx.x * 4 + wid;
    const int row0 = tile * 16;
    if (row0 >= n) return;

    const int l16 = lane & 15;
    const int lh  = lane >> 4;

    if (row0 + 16 <= n) {
        const int row = row0 + l16;
        const float4* fr = reinterpret_cast<const float4*>(feat) + (size_t)row * (IN_FEAT / 4);

        float4 ra[8][2];
        #pragma unroll
        for (int ks = 0; ks < 8; ++ks) {
            ra[ks][0] = fr[ks * 8 + lh * 2];
            ra[ks][1] = fr[ks * 8 + lh * 2 + 1];
        }

        f32x4 acc0 = {0.f, 0.f, 0.f, 0.f};
        f32x4 acc1 = {0.f, 0.f, 0.f, 0.f};

        #pragma unroll
        for (int ks = 0; ks < 8; ++ks) {
            union { short8 s; unsigned u[4]; } af;
            af.u[0] = cvt_pk_bf16(ra[ks][0].x, ra[ks][0].y);
            af.u[1] = cvt_pk_bf16(ra[ks][0].z, ra[ks][0].w);
            af.u[2] = cvt_pk_bf16(ra[ks][1].x, ra[ks][1].y);
            af.u[3] = cvt_pk_bf16(ra[ks][1].z, ra[ks][1].w);

            const int k0 = ks * 32 + lh * 8;
            short8 b0 = *reinterpret_cast<const short8*>(&sWT[l16][k0]);
            short8 b1 = *reinterpret_cast<const short8*>(&sWT[16 + l16][k0]);

            acc0 = __builtin_amdgcn_mfma_f32_16x16x32_bf16(af.s, b0, acc0, 0, 0, 0);
            acc1 = __builtin_amdgcn_mfma_f32_16x16x32_bf16(af.s, b1, acc1, 0, 0, 0);
        }

        #pragma unroll
        for (int r = 0; r < 4; ++r) {
            const size_t orow = (size_t)(row0 + lh * 4 + r) * OUT_FEAT;
            nt_store_f32(&x[orow + l16],      acc0[r]);
            nt_store_f32(&x[orow + 16 + l16], acc1[r]);
        }
    } else {
        const int rows = n - row0;
        for (int idx = lane; idx < rows * OUT_FEAT; idx += 64) {
            const int r = idx >> 5, j = idx & 31;
            float a = 0.f;
            for (int k = 0; k < IN_FEAT; ++k) {
                unsigned wb = ((unsigned)(unsigned short)sWT[j][k]) << 16;
                a += feat[(size_t)(row0 + r) * IN_FEAT + k] * __uint_as_float(wb);
            }
            x[(size_t)(row0 + r) * OUT_FEAT + j] = a;
        }
    }
}

// ---------------------------------------------------------------------------
// Kernel 2: partition edges into 256-row buckets (row>>8). 512 threads x
//   4096-edge chunk (8/thread in regs). LDS counting sort -> copy-out in
//   bucket order: runs of ~10.5 entries at consecutive global addresses
//   (line-granular NT stores). Entry {meta=(row&255)<<17|col, valbits}.
// ---------------------------------------------------------------------------
__global__ __launch_bounds__(512) void part1_kernel(
    const float* __restrict__ vals,
    const int* __restrict__ erow,
    const int* __restrict__ ecol,
    uint2* __restrict__ buf1,
    unsigned* __restrict__ cnt1,
    unsigned* __restrict__ ocnt,
    uint4* __restrict__ obuf,
    int n_edges, int nc)
{
    __shared__ uint2 sE[L1_CHUNK];                 // 32 KB
    __shared__ unsigned short sBkt[L1_CHUNK];      // 8 KB
    __shared__ unsigned sHist[NC_MAX], sBase[NC_MAX], sCur[NC_MAX], sGBase[NC_MAX];  // 8 KB

    const int tid = threadIdx.x;
    const int chunk0 = blockIdx.x * L1_CHUNK;
    const int nq = n_edges >> 2;

    for (int b = tid; b < nc; b += 512) { sHist[b] = 0; sCur[b] = 0; }
    __syncthreads();

    // 8 edges per thread (2x {int4,int4,float4})
    int4 r4[2]; int4 c4[2]; float4 v4[2];
    #pragma unroll
    for (int i = 0; i < 2; ++i) {
        const int qi = (chunk0 >> 2) + tid + i * 512;
        if (qi < nq) {
            r4[i] = reinterpret_cast<const int4*>(erow)[qi];
            c4[i] = reinterpret_cast<const int4*>(ecol)[qi];
            v4[i] = reinterpret_cast<const float4*>(vals)[qi];
        } else {
            r4[i] = make_int4(-1, -1, -1, -1);
            c4[i] = make_int4(0, 0, 0, 0);
            v4[i] = make_float4(0.f, 0.f, 0.f, 0.f);
        }
    }

    // histogram
    #pragma unroll
    for (int i = 0; i < 2; ++i) {
        const int* rr = &r4[i].x;
        #pragma unroll
        for (int t = 0; t < 4; ++t)
            if (rr[t] >= 0) atomicAdd(&sHist[rr[t] >> 8], 1u);
    }
    __syncthreads();

    // exclusive prefix (serial, nc<=512)
    if (tid == 0) {
        unsigned s = 0;
        for (int b = 0; b < nc; ++b) { sBase[b] = s; s += sHist[b]; }
    }
    __syncthreads();

    // reserve global ranges (one atomic per non-empty bucket)
    for (int b = tid; b < nc; b += 512)
        sGBase[b] = sHist[b] ? atomicAdd(&cnt1[(size_t)b * CNT_STRIDE], sHist[b]) : 0u;
    __syncthreads();

    // place entries bucket-sorted in LDS
    #pragma unroll
    for (int i = 0; i < 2; ++i) {
        const int*   rr = &r4[i].x;
        const int*   cc = &c4[i].x;
        const float* vv = &v4[i].x;
        #pragma unroll
        for (int t = 0; t < 4; ++t) {
            const int r = rr[t];
            if (r >= 0) {
                const int cb = r >> 8;
                unsigned p = sBase[cb] + atomicAdd(&sCur[cb], 1u);
                sE[p] = make_uint2(((unsigned)(r & 255) << 17) | (unsigned)cc[t],
                                   __float_as_uint(vv[t]));
                sBkt[p] = (unsigned short)cb;
            }
        }
    }
    __syncthreads();

    // coalesced copy-out: runs of same bucket -> consecutive global addrs
    int total = n_edges - chunk0;
    if (total > L1_CHUNK) total = L1_CHUNK;
    for (int p = tid; p < total; p += 512) {
        const int cb = sBkt[p];
        const unsigned g = sGBase[cb] + (p - sBase[cb]);
        const uint2 e = sE[p];
        if (g < CAPC) {
            nt_store_u64(&buf1[(size_t)cb * CAPC + g], e);
        } else {
            unsigned o = atomicAdd(ocnt, 1u);
            if (o < OCAP)
                obuf[o] = make_uint4(((unsigned)cb << 8) | (e.x >> 17),
                                     e.x & 0x1FFFFu, e.y, 0u);
        }
    }

    // scalar tail (n_edges % 4; none for 1.6M) via overflow list
    if (blockIdx.x == 0 && tid < (n_edges & 3)) {
        const int e = (nq << 2) + tid;
        unsigned o = atomicAdd(ocnt, 1u);
        if (o < OCAP)
            obuf[o] = make_uint4((unsigned)erow[e], (unsigned)ecol[e],
                                 __float_as_uint(vals[e]), 0u);
    }
}

// ---------------------------------------------------------------------------
// Kernel 3: consumer. One block per 256-row bucket, 1024 threads = 32 groups.
//   acc[256][32] (32 KB) + chunked LDS staging of entries (16 KB).
//   Inner loop: LDS-broadcast entry (free) + 8 independent x-gathers
//   (128 B per group-instr) + conflict-free LDS atomics (bank == j).
//   Non-atomic full-coverage float4 out write (no memset needed).
// ---------------------------------------------------------------------------
__global__ __launch_bounds__(1024) void spmm_consumer_kernel(
    const uint2* __restrict__ buf1,
    const unsigned* __restrict__ cnt1,
    const float* __restrict__ x,
    float* __restrict__ out,
    int n_nodes)
{
    __shared__ float acc[RBC * OUT_FEAT];   // 32 KB
    __shared__ uint2 se[SCH];               // 16 KB

    const int tid = threadIdx.x;
    const int b = blockIdx.x;

    unsigned n = cnt1[(size_t)b * CNT_STRIDE];
    if (n > CAPC) n = CAPC;

    #pragma unroll
    for (int i = 0; i < (RBC * OUT_FEAT) / 1024; ++i) acc[tid + i * 1024] = 0.f;

    const uint2* eb = buf1 + (size_t)b * CAPC;
    const int g = tid >> 5;   // group 0..31
    const int j = tid & 31;   // feature

    for (unsigned c0 = 0; c0 < n; c0 += SCH) {
        int m = (int)(n - c0);
        if (m > SCH) m = SCH;

        __syncthreads();   // previous chunk fully consumed
        if (tid < m) se[tid] = eb[c0 + tid];
        if (tid + 1024 < m) se[tid + 1024] = eb[c0 + tid + 1024];
        __syncthreads();

        int i = g;
        for (; i + 224 < m; i += 256) {
            uint2 p[8];
            float xv[8];
            #pragma unroll
            for (int k = 0; k < 8; ++k) p[k] = se[i + 32 * k];
            #pragma unroll
            for (int k = 0; k < 8; ++k)
                xv[k] = x[(size_t)(p[k].x & 0x1FFFFu) * OUT_FEAT + j];
            #pragma unroll
            for (int k = 0; k < 8; ++k)
                atomicAdd(&acc[((p[k].x >> 17) & 255u) * OUT_FEAT + j],
                          __uint_as_float(p[k].y) * xv[k]);
        }
        for (; i < m; i += 32) {
            const uint2 p = se[i];
            const float xv = x[(size_t)(p.x & 0x1FFFFu) * OUT_FEAT + j];
            atomicAdd(&acc[((p.x >> 17) & 255u) * OUT_FEAT + j],
                      __uint_as_float(p.y) * xv);
        }
    }
    __syncthreads();

    // full-coverage coalesced write of this bucket's 256 rows
    int valid = (n_nodes - b * RBC) * OUT_FEAT;
    if (valid > RBC * OUT_FEAT) valid = RBC * OUT_FEAT;
    const int v4n = valid >> 2;
    float4* out4 = reinterpret_cast<float4*>(out + (size_t)b * RBC * OUT_FEAT);
    const float4* a4 = reinterpret_cast<const float4*>(acc);
    if (tid < v4n)        out4[tid]        = a4[tid];
    if (tid + 1024 < v4n) out4[tid + 1024] = a4[tid + 1024];
}

// ---------------------------------------------------------------------------
// Kernel 4: overflow cleanup (expected zero work). Runs after consumer.
// ---------------------------------------------------------------------------
__global__ __launch_bounds__(256) void oflow_kernel(
    const uint4* __restrict__ obuf,
    const unsigned* __restrict__ ocnt,
    const float* __restrict__ x,
    float* __restrict__ out)
{
    unsigned n = *ocnt;
    if (n > OCAP) n = OCAP;
    const long long total = (long long)n * OUT_FEAT;
    const long long stride = (long long)gridDim.x * blockDim.x;
    for (long long idx = blockIdx.x * (long long)blockDim.x + threadIdx.x;
         idx < total; idx += stride) {
        const int e = (int)(idx >> 5), j = (int)(idx & 31);
        uint4 p = obuf[e];
        atomicAdd(&out[(size_t)p.x * OUT_FEAT + j],
                  __uint_as_float(p.z) * x[(size_t)p.y * OUT_FEAT + j]);
    }
}

// ---------------------------------------------------------------------------
// Fallback: flat atomic scatter (measured 171 us) if ws/shape gate fails.
// ---------------------------------------------------------------------------
__global__ __launch_bounds__(256) void spmm_scatter_kernel(
    const float* __restrict__ vals,
    const int* __restrict__ erow,
    const int* __restrict__ ecol,
    const float* __restrict__ x,
    float* __restrict__ out,
    int n_edges)
{
    const long long idx = (long long)blockIdx.x * blockDim.x + threadIdx.x;
    const int e = (int)(idx >> 5);
    const int j = (int)(idx & 31);
    if (e >= n_edges) return;
    const float m = vals[e] * x[(size_t)ecol[e] * OUT_FEAT + j];
    atomicAdd(&out[(size_t)erow[e] * OUT_FEAT + j], m);
}

// ---------------------------------------------------------------------------
extern "C" void kernel_launch(void* const* d_in, const int* in_sizes, int n_in,
                              void* d_out, int out_size, void* d_ws, size_t ws_size,
                              hipStream_t stream)
{
    const float* feat = (const float*)d_in[0];
    const float* W    = (const float*)d_in[1];
    const float* vals = (const float*)d_in[2];
    const int*   erow = (const int*)d_in[3];
    const int*   ecol = (const int*)d_in[4];
    float* out = (float*)d_out;

    const int n_nodes = in_sizes[0] / IN_FEAT;
    const int n_edges = in_sizes[2];
    const int nc = (n_nodes + RBC - 1) / RBC;     // buckets (391)

    // workspace layout (16B-aligned segments); total ~29.09 MB for this shape
    char* ws = (char*)d_ws;
    size_t off = 0;
    auto alloc = [&](size_t bytes) { size_t o = off; off = (off + bytes + 15) & ~(size_t)15; return o; };
    float*    x    = (float*)(ws + alloc((size_t)n_nodes * OUT_FEAT * sizeof(float)));
    uint2*    buf1 = (uint2*)(ws + alloc((size_t)nc * CAPC * sizeof(uint2)));
    size_t cnt_off = off;
    unsigned* cnt1 = (unsigned*)(ws + alloc((size_t)nc * CNT_STRIDE * sizeof(unsigned)));
    unsigned* ocnt = (unsigned*)(ws + alloc(sizeof(unsigned)));
    size_t cnt_end = (size_t)((char*)ocnt - ws) + 16;
    uint4*    obuf = (uint4*)(ws + alloc((size_t)OCAP * sizeof(uint4)));

    // capacity gate: mean bucket load + 8 sigma must fit CAPC
    const double lam = (nc > 0) ? (double)n_edges / nc : 0.0;
    const bool sorted_path = (ws_size >= off) && (nc <= NC_MAX) &&
                             (lam + 8.0 * sqrt(lam + 1.0) <= (double)CAPC);

    // 1) x = feat @ W  (bf16 MFMA)
    {
        const int tiles = (n_nodes + 15) / 16;
        dim3 grid((tiles + 3) / 4);
        gemm_mfma_kernel<<<grid, 256, 0, stream>>>(feat, W, x, n_nodes);
    }

    if (sorted_path) {
        hipMemsetAsync(ws + cnt_off, 0, cnt_end - cnt_off, stream);

        // 2) partition into 256-row buckets
        {
            const int nblk = (n_edges + L1_CHUNK - 1) / L1_CHUNK;
            part1_kernel<<<nblk, 512, 0, stream>>>(vals, erow, ecol, buf1, cnt1,
                                                   ocnt, obuf, n_edges, nc);
        }
        // 3) per-bucket LDS accumulation + coalesced out write
        spmm_consumer_kernel<<<nc, 1024, 0, stream>>>(buf1, cnt1, x, out, n_nodes);
        // 4) overflow cleanup (expected empty)
        oflow_kernel<<<64, 256, 0, stream>>>(obuf, ocnt, x, out);
    } else {
        hipMemsetAsync(d_out, 0, (size_t)out_size * sizeof(float), stream);
        long long total = (long long)n_edges * OUT_FEAT;
        spmm_scatter_kernel<<<(unsigned)((total + 255) / 256), 256, 0, stream>>>(
            vals, erow, ecol, x, out, n_edges);
    }
}